// Round 1
// baseline (380.090 us; speedup 1.0000x reference)
//
#include <hip/hip_runtime.h>

// Problem constants (fixed by setup_inputs): N=8, Z=128, H=W=160, 81 shifts.
#define NB 8
#define ZD 128
#define HD 160
#define WD 160
#define TI 16            // tile rows per block
#define TJ 32            // tile cols per block
#define ZC 8             // z-chunk staged in LDS
#define BR (TI + 8)      // 24 B rows (halo +-4)
#define AS 36            // A LDS row stride (pad: uniform banks, 16B-aligned rows)
#define BS 44            // B LDS row stride (40 used, pad: uniform banks, 16B-aligned)
#define NTHREADS 576     // 9 waves: wave w handles dy index w

// out[n,k,i,j] = sum_z A[n,z,i,j] * B[n,z, i + (k%9-4), j + (k//9-4)], zero-padded.
__global__ __launch_bounds__(NTHREADS)
void corr_vol_kernel(const float* __restrict__ A, const float* __restrict__ B,
                     float* __restrict__ out) {
    __shared__ float Alds[ZC][TI][AS];   // 18.4 KB
    __shared__ float Blds[ZC][BR][BS];   // 33.8 KB

    const int tid = threadIdx.x;
    const int bid = blockIdx.x;
    const int jt = bid % 5;              // W/TJ = 5
    const int it = (bid / 5) % 10;       // H/TI = 10
    const int n  = bid / 50;
    const int i0 = it * TI;
    const int j0 = jt * TJ;

    const float* Abase = A + (size_t)n * ZD * HD * WD;
    const float* Bbase = B + (size_t)n * ZD * HD * WD;

    const int w = tid >> 6;              // wave id = dy index (0..8)
    const int l = tid & 63;
    const int g = l & 3;                 // col group: cols j0+8g .. j0+8g+7
    const int r = l >> 2;                // pixel row 0..15

    float acc[9][8];                     // [dx index][pixel col]
    #pragma unroll
    for (int d = 0; d < 9; ++d)
        #pragma unroll
        for (int p = 0; p < 8; ++p) acc[d][p] = 0.f;

    for (int zb = 0; zb < ZD; zb += ZC) {
        // ---- stage A tile: ZC*16*32 floats = 1024 float4, fully in-bounds ----
        for (int idx = tid; idx < ZC * TI * (TJ / 4); idx += NTHREADS) {
            const int c4 = idx & 7;
            const int rr = (idx >> 3) & 15;
            const int zz = idx >> 7;
            const float4 v = *(const float4*)&Abase[((size_t)(zb + zz) * HD + (i0 + rr)) * WD + j0 + 4 * c4];
            *(float4*)&Alds[zz][rr][4 * c4] = v;
        }
        // ---- stage B halo tile: rows i0-4..i0+19, cols j0-4..j0+35 (zero pad OOB) ----
        for (int idx = tid; idx < ZC * BR * 10; idx += NTHREADS) {
            const int c4 = idx % 10;
            const int t  = idx / 10;
            const int rr = t % BR;
            const int zz = t / BR;
            const int gr = i0 + rr - 4;
            const int gc = j0 + 4 * c4 - 4;       // multiple of 4: float4 fully in or out
            float4 v = make_float4(0.f, 0.f, 0.f, 0.f);
            if ((unsigned)gr < (unsigned)HD && (unsigned)gc < (unsigned)WD)
                v = *(const float4*)&Bbase[((size_t)(zb + zz) * HD + gr) * WD + gc];
            *(float4*)&Blds[zz][rr][4 * c4] = v;
        }
        __syncthreads();

        #pragma unroll 2
        for (int z = 0; z < ZC; ++z) {
            float a[8], b[16];
            *(float4*)&a[0] = *(const float4*)&Alds[z][r][8 * g];
            *(float4*)&a[4] = *(const float4*)&Alds[z][r][8 * g + 4];
            const int br = r + w;                 // B row = i0 + r + (w-4), halo offset +4
            *(float4*)&b[0]  = *(const float4*)&Blds[z][br][8 * g];
            *(float4*)&b[4]  = *(const float4*)&Blds[z][br][8 * g + 4];
            *(float4*)&b[8]  = *(const float4*)&Blds[z][br][8 * g + 8];
            *(float4*)&b[12] = *(const float4*)&Blds[z][br][8 * g + 12];
            // strip b[] covers cols j0+8g-4 .. j0+8g+11; pixel p col = j0+8g+p; dx = d-4
            #pragma unroll
            for (int d = 0; d < 9; ++d)
                #pragma unroll
                for (int p = 0; p < 8; ++p)
                    acc[d][p] = fmaf(a[p], b[p + d], acc[d][p]);
        }
        __syncthreads();
    }

    // ---- epilogue: k = d*9 + w  (k//9 = dx index, k%9 = dy index) ----
    float* obase = out + (((size_t)n * 81) * HD + (i0 + r)) * WD + j0 + 8 * g;
    #pragma unroll
    for (int d = 0; d < 9; ++d) {
        const int k = d * 9 + w;
        float* o = obase + (size_t)k * HD * WD;
        *(float4*)&o[0] = make_float4(acc[d][0], acc[d][1], acc[d][2], acc[d][3]);
        *(float4*)&o[4] = make_float4(acc[d][4], acc[d][5], acc[d][6], acc[d][7]);
    }
}

extern "C" void kernel_launch(void* const* d_in, const int* in_sizes, int n_in,
                              void* d_out, int out_size, void* d_ws, size_t ws_size,
                              hipStream_t stream) {
    const float* A = (const float*)d_in[0];
    const float* B = (const float*)d_in[1];
    float* out = (float*)d_out;
    corr_vol_kernel<<<dim3(NB * 10 * 5), dim3(NTHREADS), 0, stream>>>(A, B, out);
}

// Round 2
// 368.710 us; speedup vs baseline: 1.0309x; 1.0309x over previous
//
#include <hip/hip_runtime.h>

// N=8, Z=128, H=W=160, 81 integer shifts (grid-sample degenerates to exact
// integer displacement because (max_disp scale) * (W-1)/2 is integral).
#define NB 8
#define ZD 128
#define HD 160
#define WD 160
#define TI 16             // tile rows
#define TJ 32             // tile cols
#define ZC 4              // z per chunk (double-buffered)
#define NCHUNK (ZD / ZC)  // 32
#define BR (TI + 8)       // 24 B rows (halo +-4)
#define ASL 9             // A 16B-slots per row (8 data + 1 pad) -> 36-float stride
#define BSL 11            // B 16B-slots per row (10 data + 1 pad) -> 44-float stride
#define A_SLOTS (ZC * TI * ASL)  // 576
#define B_SLOTS (ZC * BR * BSL)  // 1056
#define NTHREADS 576      // 9 waves; wave w = dy index
#define CHUNK_ELEMS (ZC * HD * WD)

#define GP(x) ((const __attribute__((address_space(1))) void*)(x))
#define LP(x) ((__attribute__((address_space(3))) void*)(x))

__global__ __launch_bounds__(NTHREADS, 4)
void corr_vol_kernel(const float* __restrict__ A, const float* __restrict__ B,
                     float* __restrict__ out) {
    __shared__ float4 Albuf[2][A_SLOTS];   // 18.4 KB
    __shared__ float4 Blbuf[2][B_SLOTS];   // 33.8 KB   (total 52224 B)

    const int tid = threadIdx.x;
    const int bid = blockIdx.x;
    const int jt = bid % 5;
    const int it = (bid / 5) % 10;
    const int n  = bid / 50;
    const int i0 = it * TI;
    const int j0 = jt * TJ;

    const float* Abase = A + (size_t)n * ZD * HD * WD;
    const float* Bbase = B + (size_t)n * ZD * HD * WD;

    // ---- zero B regions of both buffers (halo/pad slots are never loaded) ----
    const float4 z4 = make_float4(0.f, 0.f, 0.f, 0.f);
    for (int s = tid; s < 2 * B_SLOTS; s += NTHREADS) ((float4*)Blbuf)[s] = z4;

    // ---- per-thread staging descriptors (constant across chunks) ----
    // A: slot s = tid -> (z, row, col-slot); pad slot clamps to col 28 (dup, never read)
    const int zA = tid / (TI * ASL);
    const int rA = (tid / ASL) % TI;
    const int cA = tid % ASL;
    const int colA = (cA < 8) ? 4 * cA : 28;
    const float* gA = Abase + ((size_t)zA * HD + (i0 + rA)) * WD + j0 + colA;
    const unsigned ldsA = (unsigned)(tid & ~63);

    // B: slots s = tid and tid+576 -> (z, row, col-slot); mask pad + OOB (stay zero)
    const int s1 = tid, s2 = tid + NTHREADS;
    const int zB1 = s1 / (BR * BSL), rB1 = (s1 / BSL) % BR, cB1 = s1 % BSL;
    const int zB2 = s2 / (BR * BSL), rB2 = (s2 / BSL) % BR, cB2 = s2 % BSL;
    const int gr1 = i0 + rB1 - 4, gc1 = j0 + 4 * cB1 - 4;
    const int gr2 = i0 + rB2 - 4, gc2 = j0 + 4 * cB2 - 4;
    const bool vB1 = (cB1 < 10) && ((unsigned)gr1 < HD) && ((unsigned)gc1 < WD);
    const bool vB2 = (s2 < B_SLOTS) && (cB2 < 10) && ((unsigned)gr2 < HD) && ((unsigned)gc2 < WD);
    const float* gB1 = Bbase + ((size_t)zB1 * HD + gr1) * WD + gc1;
    const float* gB2 = Bbase + ((size_t)zB2 * HD + gr2) * WD + gc2;
    const unsigned ldsB1 = (unsigned)(s1 & ~63);
    const unsigned ldsB2 = (unsigned)(s2 & ~63);

    // compute-phase lane mapping
    const int w = tid >> 6;        // dy index 0..8
    const int l = tid & 63;
    const int g = l & 3;           // col group (8 cols)
    const int r = l >> 2;          // pixel row 0..15

    float acc[9][8];
    #pragma unroll
    for (int d = 0; d < 9; ++d)
        #pragma unroll
        for (int p = 0; p < 8; ++p) acc[d][p] = 0.f;

    __syncthreads();   // zero-init visible before any async load lands

    // ---- prefetch chunk 0 into buffer 0 ----
    {
        __builtin_amdgcn_global_load_lds(GP(gA), LP((char*)&Albuf[0][0] + 16u * ldsA), 16, 0, 0);
        if (vB1) __builtin_amdgcn_global_load_lds(GP(gB1), LP((char*)&Blbuf[0][0] + 16u * ldsB1), 16, 0, 0);
        if (vB2) __builtin_amdgcn_global_load_lds(GP(gB2), LP((char*)&Blbuf[0][0] + 16u * ldsB2), 16, 0, 0);
        gA += CHUNK_ELEMS; gB1 += CHUNK_ELEMS; gB2 += CHUNK_ELEMS;
    }

    for (int k = 0; k < NCHUNK; ++k) {
        __syncthreads();   // chunk k resident; buf[(k+1)&1] no longer being read
        if (k + 1 < NCHUNK) {
            const int pb = (k + 1) & 1;
            __builtin_amdgcn_global_load_lds(GP(gA), LP((char*)&Albuf[pb][0] + 16u * ldsA), 16, 0, 0);
            if (vB1) __builtin_amdgcn_global_load_lds(GP(gB1), LP((char*)&Blbuf[pb][0] + 16u * ldsB1), 16, 0, 0);
            if (vB2) __builtin_amdgcn_global_load_lds(GP(gB2), LP((char*)&Blbuf[pb][0] + 16u * ldsB2), 16, 0, 0);
            gA += CHUNK_ELEMS; gB1 += CHUNK_ELEMS; gB2 += CHUNK_ELEMS;
        }
        const float* Af = (const float*)&Albuf[k & 1][0];
        const float* Bf = (const float*)&Blbuf[k & 1][0];
        #pragma unroll
        for (int z = 0; z < ZC; ++z) {
            float a[8], b[16];
            const float* ap = Af + z * (TI * ASL * 4) + r * (ASL * 4) + 8 * g;
            const float* bp = Bf + z * (BR * BSL * 4) + (r + w) * (BSL * 4) + 8 * g;
            *(float4*)&a[0] = *(const float4*)&ap[0];
            *(float4*)&a[4] = *(const float4*)&ap[4];
            *(float4*)&b[0]  = *(const float4*)&bp[0];
            *(float4*)&b[4]  = *(const float4*)&bp[4];
            *(float4*)&b[8]  = *(const float4*)&bp[8];
            *(float4*)&b[12] = *(const float4*)&bp[12];
            #pragma unroll
            for (int d = 0; d < 9; ++d)
                #pragma unroll
                for (int p = 0; p < 8; ++p)
                    acc[d][p] = fmaf(a[p], b[p + d], acc[d][p]);
        }
    }

    // ---- epilogue: k = d*9 + w ----
    float* obase = out + (((size_t)n * 81) * HD + (i0 + r)) * WD + j0 + 8 * g;
    #pragma unroll
    for (int d = 0; d < 9; ++d) {
        const int kk = d * 9 + w;
        float* o = obase + (size_t)kk * HD * WD;
        *(float4*)&o[0] = make_float4(acc[d][0], acc[d][1], acc[d][2], acc[d][3]);
        *(float4*)&o[4] = make_float4(acc[d][4], acc[d][5], acc[d][6], acc[d][7]);
    }
}

extern "C" void kernel_launch(void* const* d_in, const int* in_sizes, int n_in,
                              void* d_out, int out_size, void* d_ws, size_t ws_size,
                              hipStream_t stream) {
    const float* A = (const float*)d_in[0];
    const float* B = (const float*)d_in[1];
    float* out = (float*)d_out;
    corr_vol_kernel<<<dim3(NB * 10 * 5), dim3(NTHREADS), 0, stream>>>(A, B, out);
}

// Round 3
// 356.093 us; speedup vs baseline: 1.0674x; 1.0354x over previous
//
#include <hip/hip_runtime.h>

// N=8, Z=128, H=W=160, 81 integer shifts (grid-sample degenerates to exact
// integer displacements at H=W=160).
#define NB 8
#define ZD 128
#define HD 160
#define WD 160
#define TI 16
#define TJ 32
#define ZC 2
#define NCHUNK (ZD / ZC)          // 64
#define BR (TI + 8)               // 24 B rows (halo +-4)
#define ASL 9                     // A 16B-slots/row (8 data + 1 pad) -> 36-float stride
#define BSL 11                    // B 16B-slots/row (10 data + 1 pad) -> 44-float stride
#define A_SLOTS (ZC * TI * ASL)   // 288
#define B_SLOTS (ZC * BR * BSL)   // 528
#define BUF_SLOTS 832             // 288+528=816 real, pad to 13*64 (wave-uniform dests)
#define NBUF 3                    // prefetch distance 2
#define NTHREADS 576              // 9 waves; wave w = dy index
#define CHUNK_ELEMS (ZC * HD * WD)

#define GP(x) ((const __attribute__((address_space(1))) void*)(x))
#define LP(x) ((__attribute__((address_space(3))) void*)(x))

__global__ __launch_bounds__(NTHREADS, 4)
void corr_vol_kernel(const float* __restrict__ A, const float* __restrict__ B,
                     const float* __restrict__ zp, float* __restrict__ out) {
    __shared__ float4 lds[NBUF * BUF_SLOTS];   // 39 KB
    __shared__ float4 dump[64];                // write-only sink (tail dummies)

    const int tid = threadIdx.x;
    const int bid = blockIdx.x;
    const int jt = bid % 5;
    const int it = (bid / 5) % 10;
    const int n  = bid / 50;
    const int i0 = it * TI;
    const int j0 = jt * TJ;

    const float* Abase = A + (size_t)n * ZD * HD * WD;
    const float* Bbase = B + (size_t)n * ZD * HD * WD;

    // ---- load-1 descriptor: LDS slot s1 = tid (A region [0,288) then B [288,816)) ----
    const float* p1; int st1;
    if (tid < A_SLOTS) {
        const int a = tid, zA = a / (TI * ASL), rA = (a / ASL) % TI, cA = a % ASL;
        const bool v = (cA < 8);
        p1 = v ? (Abase + ((size_t)zA * HD + (i0 + rA)) * WD + j0 + 4 * cA) : zp;
        st1 = v ? CHUNK_ELEMS : 0;
    } else {
        const int q = tid - A_SLOTS;
        const int z = q / (BR * BSL), rw = (q / BSL) % BR, c = q % BSL;
        const int gr = i0 + rw - 4, gc = j0 + 4 * c - 4;
        const bool v = (c < 10) && ((unsigned)gr < (unsigned)HD) && ((unsigned)gc < (unsigned)WD);
        p1 = v ? (Bbase + ((size_t)z * HD + gr) * WD + gc) : zp;
        st1 = v ? CHUNK_ELEMS : 0;
    }
    // ---- load-2 descriptor: slot s2 = tid + 576 (B region tail; waves >= 832 -> dump) ----
    const int s2 = tid + NTHREADS;
    const int q2 = s2 - A_SLOTS;
    const int z2 = q2 / (BR * BSL), rw2 = (q2 / BSL) % BR, c2 = q2 % BSL;
    const int gr2 = i0 + rw2 - 4, gc2 = j0 + 4 * c2 - 4;
    const bool v2 = (q2 < B_SLOTS) && (c2 < 10) &&
                    ((unsigned)gr2 < (unsigned)HD) && ((unsigned)gc2 < (unsigned)WD);
    const float* p2 = v2 ? (Bbase + ((size_t)z2 * HD + gr2) * WD + gc2) : zp;
    const int st2 = v2 ? CHUNK_ELEMS : 0;
    const bool s2_in = (s2 < BUF_SLOTS);         // wave-uniform (832 = 13*64)
    const unsigned d1 = (unsigned)(tid & ~63);
    const unsigned d2 = (unsigned)(s2 & ~63);

    // Every thread issues EXACTLY 2 global_load_lds per prefetch -> exact vmcnt math.
    auto prefetch = [&](int k2, int pb) {
        if (k2 < NCHUNK) {
            char* base = (char*)&lds[pb * BUF_SLOTS];
            __builtin_amdgcn_global_load_lds(GP(p1 + (size_t)k2 * st1),
                                             LP(base + 16u * d1), 16, 0, 0);
            __builtin_amdgcn_global_load_lds(GP(p2 + (size_t)k2 * st2),
                                             LP(s2_in ? (base + 16u * d2) : (char*)&dump[0]), 16, 0, 0);
        } else {  // tail dummies keep per-wave outstanding-count uniform
            __builtin_amdgcn_global_load_lds(GP(zp), LP((char*)&dump[0]), 16, 0, 0);
            __builtin_amdgcn_global_load_lds(GP(zp), LP((char*)&dump[0]), 16, 0, 0);
        }
    };

    const int w = tid >> 6;       // dy index 0..8
    const int l = tid & 63;
    const int g = l & 3;          // col group (8 cols)
    const int r = l >> 2;         // pixel row 0..15

    float acc[9][8];
    #pragma unroll
    for (int d = 0; d < 9; ++d)
        #pragma unroll
        for (int p = 0; p < 8; ++p) acc[d][p] = 0.f;

    prefetch(0, 0);
    prefetch(1, 1);

    for (int k = 0; k < NCHUNK; ++k) {
        // Wait ONLY for the oldest prefetch (2 loads) -> chunk k resident; the
        // younger prefetch stays in flight across the barrier (distance-2).
        asm volatile("s_waitcnt vmcnt(2)\n\ts_barrier" ::: "memory");
        prefetch(k + 2, (k + 2) % 3);

        const float* Af = (const float*)&lds[(k % 3) * BUF_SLOTS];
        const float* Bf = Af + 4 * A_SLOTS;
        #pragma unroll
        for (int z = 0; z < ZC; ++z) {
            float a[8], b[16];
            const float* ap = Af + z * (TI * ASL * 4) + r * (ASL * 4) + 8 * g;
            const float* bp = Bf + z * (BR * BSL * 4) + (r + w) * (BSL * 4) + 8 * g;
            *(float4*)&a[0] = *(const float4*)&ap[0];
            *(float4*)&a[4] = *(const float4*)&ap[4];
            *(float4*)&b[0]  = *(const float4*)&bp[0];
            *(float4*)&b[4]  = *(const float4*)&bp[4];
            *(float4*)&b[8]  = *(const float4*)&bp[8];
            *(float4*)&b[12] = *(const float4*)&bp[12];
            #pragma unroll
            for (int d = 0; d < 9; ++d)
                #pragma unroll
                for (int p = 0; p < 8; ++p)
                    acc[d][p] = fmaf(a[p], b[p + d], acc[d][p]);
        }
    }
    asm volatile("s_waitcnt vmcnt(0)" ::: "memory");  // tail dummies before LDS teardown

    // ---- epilogue: k = d*9 + w ----
    float* obase = out + (((size_t)n * 81) * HD + (i0 + r)) * WD + j0 + 8 * g;
    #pragma unroll
    for (int d = 0; d < 9; ++d) {
        const int kk = d * 9 + w;
        float* o = obase + (size_t)kk * HD * WD;
        *(float4*)&o[0] = make_float4(acc[d][0], acc[d][1], acc[d][2], acc[d][3]);
        *(float4*)&o[4] = make_float4(acc[d][4], acc[d][5], acc[d][6], acc[d][7]);
    }
}

extern "C" void kernel_launch(void* const* d_in, const int* in_sizes, int n_in,
                              void* d_out, int out_size, void* d_ws, size_t ws_size,
                              hipStream_t stream) {
    const float* A = (const float*)d_in[0];
    const float* B = (const float*)d_in[1];
    float* out = (float*)d_out;
    // 256 B zero page for OOB/pad staging lanes (d_ws is re-poisoned every launch).
    hipMemsetAsync(d_ws, 0, 256, stream);
    corr_vol_kernel<<<dim3(NB * 10 * 5), dim3(NTHREADS), 0, stream>>>(
        A, B, (const float*)d_ws, out);
}